// Round 2
// baseline (2026.811 us; speedup 1.0000x reference)
//
#include <hip/hip_runtime.h>

typedef _Float16 h8 __attribute__((ext_vector_type(8)));
typedef _Float16 h4 __attribute__((ext_vector_type(4)));
typedef float    f4 __attribute__((ext_vector_type(4)));
typedef unsigned u4 __attribute__((ext_vector_type(4)));

#define NT     512
#define OUT0   33554432   // 64*512*1024

__device__ __forceinline__ float sigm(float x)  { return 1.0f / (1.0f + __expf(-x)); }
__device__ __forceinline__ float tanhf_(float x){ float e = __expf(2.0f * x); return 1.0f - 2.0f / (e + 1.0f); }

// ---------------- prep kernels ----------------

__global__ __launch_bounds__(256) void xconv_k(const float* __restrict__ x, _Float16* __restrict__ x16) {
    size_t i = ((size_t)blockIdx.x * 256 + threadIdx.x) * 4;
    f4 v = *(const f4*)(x + i);
    h4 o; o[0] = (_Float16)v[0]; o[1] = (_Float16)v[1]; o[2] = (_Float16)v[2]; o[3] = (_Float16)v[3];
    *(h4*)(x16 + i) = o;
}

// wcat16[dir][p][k], p = j*4 + gate, k<512 -> Wih, else Whh
__global__ __launch_bounds__(256) void wconv_k(const float* __restrict__ Wih_f, const float* __restrict__ Whh_f,
                                               const float* __restrict__ Wih_b, const float* __restrict__ Whh_b,
                                               _Float16* __restrict__ wcat) {
    size_t e = (size_t)blockIdx.x * 256 + threadIdx.x;
    int k4  = (int)(e & 255);
    int p   = (int)((e >> 8) & 2047);
    int dir = (int)(e >> 19);
    int gate = p & 3, j = p >> 2;
    int k = k4 * 4;
    const float* Wih = dir ? Wih_b : Wih_f;
    const float* Whh = dir ? Whh_b : Whh_f;
    f4 v;
    if (k < 512) v = *(const f4*)&Wih[((size_t)gate * 512 + j) * 512 + k];
    else         v = *(const f4*)&Whh[((size_t)gate * 512 + j) * 512 + (k - 512)];
    h4 o; o[0] = (_Float16)v[0]; o[1] = (_Float16)v[1]; o[2] = (_Float16)v[2]; o[3] = (_Float16)v[3];
    *(h4*)&wcat[(((size_t)dir * 2048) + p) * 1024 + k] = o;
}

// tagged ring init: rb[slot][dir][b][j] u32 = (tag16<<16)|fp16(h)
// slot0 = tag 0 with h0; slot1 = invalid tag 0xFFFF
__global__ __launch_bounds__(256) void initring_k(const float* __restrict__ enc_h, unsigned* __restrict__ rb) {
    int e = blockIdx.x * 256 + threadIdx.x;   // 0..65535
    float v = enc_h[e];
    int b = e >> 10, q = e & 1023, dir = q >> 9, j = q & 511;
    unsigned short hb = __builtin_bit_cast(unsigned short, (_Float16)v);
    size_t idx = ((size_t)dir * 64 + b) * 512 + j;
    rb[idx]         = (unsigned)hb;       // slot 0, tag 0
    rb[idx + 65536] = 0xFFFF0000u;        // slot 1, never-matching tag
}

// ---------------- persistent bidirectional LSTM scan ----------------
// 256 blocks (1/CU): grp = bx&7 -> (dir,mg) so each sync group of 32 blocks lands
// on one XCD under round-robin dispatch (perf-only: x16 L2 locality; comm stays
// device-scope sc0 sc1). Block: M=16 batches, N=64 gate rows, K=1024; 4 waves
// split K. Weights pinned in VGPRs all 512 steps.
// Sync: 512 KB depth-2 tagged ring. Element u32 = (tag<<16)|fp16(h); consumer
// polls until every element's tag == t. Depth-2 reuse is race-free: publishing
// h(t+1) implies the publisher consumed h(t), which implies everyone published
// h(t), which implies everyone consumed h(t-1) -> the slot being overwritten is
// dead. First poll batch is issued BEFORE the x-MFMAs so the drain of our own
// previous sc1 stores (vmcnt retires in order!) overlaps MFMA instead of
// serializing the step.
__global__ __launch_bounds__(256, 1) void lstm_persist(
    const _Float16* __restrict__ x16, const _Float16* __restrict__ wcat,
    const float* __restrict__ b_f, const float* __restrict__ b_b,
    const float* __restrict__ enc_c, unsigned* __restrict__ rb,
    float* __restrict__ out, float* __restrict__ hseg, float* __restrict__ cseg)
{
    const int bx  = blockIdx.x;
    const int grp = bx & 7;                    // XCD-local group
    const int dir = grp >> 2, mg = grp & 3, ng = bx >> 3;
    const int b0 = mg * 16, p0 = ng * 64, j0 = ng * 16;
    const int tid = threadIdx.x, lane = tid & 63, kw = tid >> 6;
    const int l15 = lane & 15, koff = (lane >> 4) * 8;

    __shared__ float gbuf[2][4][16][68];   // parity-double-buffered split-K partials

    // ---- one-time: B fragments into registers, pinned so they survive the loop ----
    f4 wx[4][4], wh[4][4];
    #pragma unroll
    for (int nt = 0; nt < 4; ++nt) {
        const _Float16* wrow = wcat + ((size_t)dir * 2048 + p0 + nt * 16 + l15) * 1024 + kw * 128 + koff;
        #pragma unroll
        for (int s = 0; s < 4; ++s) {
            wx[nt][s] = *(const f4*)(wrow + s * 32);
            wh[nt][s] = *(const f4*)(wrow + 512 + s * 32);
        }
    }
    #pragma unroll
    for (int nt = 0; nt < 4; ++nt)
        #pragma unroll
        for (int s = 0; s < 4; ++s) {
            asm volatile("" : "+v"(wx[nt][s]));
            asm volatile("" : "+v"(wh[nt][s]));
        }

    // ---- one-time: per-thread epilogue state (thread owns (b0+mb, j0+jj)) ----
    const int mb = tid >> 4, jj = tid & 15;
    const float* bias = dir ? b_b : b_f;
    const float bi = bias[0 * 512 + j0 + jj];
    const float bf = bias[1 * 512 + j0 + jj];
    const float bg = bias[2 * 512 + j0 + jj];
    const float bo = bias[3 * 512 + j0 + jj];
    float c = enc_c[(size_t)(b0 + mb) * 1024 + dir * 512 + j0 + jj];
    float hlast = 0.f;

    // per-lane A-fragment base pointers
    const _Float16* xbase = x16 + (size_t)(b0 + l15) * NT * 512 + kw * 128 + koff;

    // prefetch x_0 fragments
    f4 xf[4];
    {
        const _Float16* xp = xbase + (size_t)(dir ? (NT - 1) : 0) * 512;
        #pragma unroll
        for (int s = 0; s < 4; ++s) xf[s] = *(const f4*)(xp + s * 32);
    }

    // poll base (slot-invariant part)
    const unsigned* pbase = rb + (size_t)dir * 32768 + (size_t)(b0 + l15) * 512 + kw * 128 + koff;
    unsigned* sbase = rb + (size_t)dir * 32768 + (size_t)(b0 + mb) * 512 + (j0 + jj);

    for (int t = 0; t < NT; ++t) {
        const int tx = dir ? (NT - 1 - t) : t;
        const unsigned* pp = pbase + (size_t)(t & 1) * 65536;

        // ---- issue first poll batch NOW (no wait) -> latency hides under x-MFMAs ----
        u4 q0, q1, q2, q3, q4, q5, q6, q7;
        asm volatile(
            "global_load_dwordx4 %0, %8, off sc0 sc1\n\t"
            "global_load_dwordx4 %1, %8, off offset:16 sc0 sc1\n\t"
            "global_load_dwordx4 %2, %8, off offset:128 sc0 sc1\n\t"
            "global_load_dwordx4 %3, %8, off offset:144 sc0 sc1\n\t"
            "global_load_dwordx4 %4, %8, off offset:256 sc0 sc1\n\t"
            "global_load_dwordx4 %5, %8, off offset:272 sc0 sc1\n\t"
            "global_load_dwordx4 %6, %8, off offset:384 sc0 sc1\n\t"
            "global_load_dwordx4 %7, %8, off offset:400 sc0 sc1"
            : "=&v"(q0), "=&v"(q1), "=&v"(q2), "=&v"(q3),
              "=&v"(q4), "=&v"(q5), "=&v"(q6), "=&v"(q7)
            : "v"(pp) : "memory");

        // ---- x-part MFMAs (overlap poll latency + our own prior store drain) ----
        f4 acc[4];
        #pragma unroll
        for (int nt = 0; nt < 4; ++nt) { acc[nt][0] = 0.f; acc[nt][1] = 0.f; acc[nt][2] = 0.f; acc[nt][3] = 0.f; }
        #pragma unroll
        for (int s = 0; s < 4; ++s) {
            h8 a = __builtin_bit_cast(h8, xf[s]);
            #pragma unroll
            for (int nt = 0; nt < 4; ++nt)
                acc[nt] = __builtin_amdgcn_mfma_f32_16x16x32_f16(a, __builtin_bit_cast(h8, wx[nt][s]), acc[nt], 0, 0, 0);
        }
        #pragma unroll
        for (int nt = 0; nt < 4; ++nt) asm volatile("" : "+v"(acc[nt]));
        __builtin_amdgcn_sched_barrier(0);

        // ---- wait + tag-check; retries are pure load round trips ----
        const unsigned tagx = (unsigned)t << 16;
        for (;;) {
            asm volatile("s_waitcnt vmcnt(0)" ::: "memory");
            __builtin_amdgcn_sched_barrier(0);   // rule #18: keep checks below the wait
            int ok = ((q0[0]^tagx)<0x10000u) & ((q0[1]^tagx)<0x10000u) & ((q0[2]^tagx)<0x10000u) & ((q0[3]^tagx)<0x10000u)
                   & ((q1[0]^tagx)<0x10000u) & ((q1[1]^tagx)<0x10000u) & ((q1[2]^tagx)<0x10000u) & ((q1[3]^tagx)<0x10000u)
                   & ((q2[0]^tagx)<0x10000u) & ((q2[1]^tagx)<0x10000u) & ((q2[2]^tagx)<0x10000u) & ((q2[3]^tagx)<0x10000u)
                   & ((q3[0]^tagx)<0x10000u) & ((q3[1]^tagx)<0x10000u) & ((q3[2]^tagx)<0x10000u) & ((q3[3]^tagx)<0x10000u)
                   & ((q4[0]^tagx)<0x10000u) & ((q4[1]^tagx)<0x10000u) & ((q4[2]^tagx)<0x10000u) & ((q4[3]^tagx)<0x10000u)
                   & ((q5[0]^tagx)<0x10000u) & ((q5[1]^tagx)<0x10000u) & ((q5[2]^tagx)<0x10000u) & ((q5[3]^tagx)<0x10000u)
                   & ((q6[0]^tagx)<0x10000u) & ((q6[1]^tagx)<0x10000u) & ((q6[2]^tagx)<0x10000u) & ((q6[3]^tagx)<0x10000u)
                   & ((q7[0]^tagx)<0x10000u) & ((q7[1]^tagx)<0x10000u) & ((q7[2]^tagx)<0x10000u) & ((q7[3]^tagx)<0x10000u);
            if (__all(ok)) break;
            asm volatile(
                "global_load_dwordx4 %0, %8, off sc0 sc1\n\t"
                "global_load_dwordx4 %1, %8, off offset:16 sc0 sc1\n\t"
                "global_load_dwordx4 %2, %8, off offset:128 sc0 sc1\n\t"
                "global_load_dwordx4 %3, %8, off offset:144 sc0 sc1\n\t"
                "global_load_dwordx4 %4, %8, off offset:256 sc0 sc1\n\t"
                "global_load_dwordx4 %5, %8, off offset:272 sc0 sc1\n\t"
                "global_load_dwordx4 %6, %8, off offset:384 sc0 sc1\n\t"
                "global_load_dwordx4 %7, %8, off offset:400 sc0 sc1\n\t"
                "s_waitcnt vmcnt(0)"
                : "=&v"(q0), "=&v"(q1), "=&v"(q2), "=&v"(q3),
                  "=&v"(q4), "=&v"(q5), "=&v"(q6), "=&v"(q7)
                : "v"(pp) : "memory");
        }

        // ---- issue x prefetch for t+1 early (drains under next step's overlap) ----
        if (t + 1 < NT) {
            const _Float16* xp = xbase + (size_t)(dir ? (NT - 2 - t) : (t + 1)) * 512;
            #pragma unroll
            for (int s = 0; s < 4; ++s) xf[s] = *(const f4*)(xp + s * 32);
        }

        // ---- pack fp16 h from low halves -> A-fragments ----
        h8 hfr[4];
        {
            u4 w;
            w[0] = (q0[0]&0xffffu)|(q0[1]<<16); w[1] = (q0[2]&0xffffu)|(q0[3]<<16);
            w[2] = (q1[0]&0xffffu)|(q1[1]<<16); w[3] = (q1[2]&0xffffu)|(q1[3]<<16);
            hfr[0] = __builtin_bit_cast(h8, w);
            w[0] = (q2[0]&0xffffu)|(q2[1]<<16); w[1] = (q2[2]&0xffffu)|(q2[3]<<16);
            w[2] = (q3[0]&0xffffu)|(q3[1]<<16); w[3] = (q3[2]&0xffffu)|(q3[3]<<16);
            hfr[1] = __builtin_bit_cast(h8, w);
            w[0] = (q4[0]&0xffffu)|(q4[1]<<16); w[1] = (q4[2]&0xffffu)|(q4[3]<<16);
            w[2] = (q5[0]&0xffffu)|(q5[1]<<16); w[3] = (q5[2]&0xffffu)|(q5[3]<<16);
            hfr[2] = __builtin_bit_cast(h8, w);
            w[0] = (q6[0]&0xffffu)|(q6[1]<<16); w[1] = (q6[2]&0xffffu)|(q6[3]<<16);
            w[2] = (q7[0]&0xffffu)|(q7[1]<<16); w[3] = (q7[2]&0xffffu)|(q7[3]<<16);
            hfr[3] = __builtin_bit_cast(h8, w);
        }

        // ---- h-part MFMAs ----
        #pragma unroll
        for (int s = 0; s < 4; ++s)
            #pragma unroll
            for (int nt = 0; nt < 4; ++nt)
                acc[nt] = __builtin_amdgcn_mfma_f32_16x16x32_f16(hfr[s], __builtin_bit_cast(h8, wh[nt][s]), acc[nt], 0, 0, 0);

        // ---- cross-wave split-K reduction via LDS (parity buffer -> 1 barrier/step) ----
        float (*gb)[16][68] = gbuf[t & 1];
        #pragma unroll
        for (int nt = 0; nt < 4; ++nt)
            #pragma unroll
            for (int r = 0; r < 4; ++r)
                gb[kw][(lane >> 4) * 4 + r][nt * 16 + l15] = acc[nt][r];
        __syncthreads();

        // ---- gates + state update (thread = (mb, jj)) ----
        float gi = bi, gf = bf, gg = bg, go = bo;
        #pragma unroll
        for (int w = 0; w < 4; ++w) {
            gi += gb[w][mb][jj * 4 + 0];
            gf += gb[w][mb][jj * 4 + 1];
            gg += gb[w][mb][jj * 4 + 2];
            go += gb[w][mb][jj * 4 + 3];
        }
        float i_ = sigm(gi), f_ = sigm(gf), o_ = sigm(go), g_ = tanhf_(gg);
        c = f_ * c + i_ * g_;
        float h = o_ * tanhf_(c);
        hlast = h;

        // ---- publish (tag<<16)|fp16(h) coherently, fire-and-forget ----
        {
            unsigned short hb = __builtin_bit_cast(unsigned short, (_Float16)h);
            unsigned uv = ((unsigned)(t + 1) << 16) | (unsigned)hb;
            unsigned* rd = sbase + (size_t)((t + 1) & 1) * 65536;
            asm volatile("global_store_dword %0, %1, off sc0 sc1" :: "v"(rd), "v"(uv) : "memory");
        }
        // plain cached store to out (off the coherent path, drained at kernel end)
        out[((size_t)(b0 + mb) * NT + tx) * 1024 + (size_t)(dir * 512 + j0 + jj)] = h;
    }

    asm volatile("s_waitcnt vmcnt(0)" ::: "memory");

    // ---- final h/c state ----
    hseg[(size_t)(b0 + mb) * 1024 + dir * 512 + j0 + jj] = hlast;
    cseg[(size_t)(b0 + mb) * 1024 + dir * 512 + j0 + jj] = c;
}

// ---------------- launcher ----------------

extern "C" void kernel_launch(void* const* d_in, const int* in_sizes, int n_in,
                              void* d_out, int out_size, void* d_ws, size_t ws_size,
                              hipStream_t stream) {
    const float* xin   = (const float*)d_in[0];
    const float* enc_h = (const float*)d_in[1];
    const float* enc_c = (const float*)d_in[2];
    const float* Wih_f = (const float*)d_in[3];
    const float* Whh_f = (const float*)d_in[4];
    const float* b_f   = (const float*)d_in[5];
    const float* Wih_b = (const float*)d_in[6];
    const float* Whh_b = (const float*)d_in[7];
    const float* b_b   = (const float*)d_in[8];

    float* out  = (float*)d_out;
    float* hseg = out + OUT0;          // final h [64,1024]
    float* cseg = hseg + 65536;        // final c [64,1024]

    const size_t X16_BYTES  = (size_t)64 * 512 * 512 * 2;        // 33,554,432
    const size_t WCAT_BYTES = (size_t)2 * 2048 * 1024 * 2;       //  8,388,608

    _Float16* x16  = (_Float16*)d_ws;
    _Float16* wcat = (_Float16*)((char*)d_ws + X16_BYTES);
    unsigned* rb   = (unsigned*)((char*)d_ws + X16_BYTES + WCAT_BYTES);  // 512 KB ring

    xconv_k<<<dim3(16384), dim3(256), 0, stream>>>(xin, x16);
    wconv_k<<<dim3(4096), dim3(256), 0, stream>>>(Wih_f, Whh_f, Wih_b, Whh_b, wcat);
    initring_k<<<dim3(256), dim3(256), 0, stream>>>(enc_h, rb);
    lstm_persist<<<dim3(256), dim3(256), 0, stream>>>(x16, wcat, b_f, b_b, enc_c,
                                                      rb, out, hseg, cseg);
}